// Round 2
// baseline (661.043 us; speedup 1.0000x reference)
//
#include <hip/hip_runtime.h>
#include <hip/hip_bf16.h>

#define S_LEN 128
#define B_SZ  32
#define VOCAB 32000
#define EMB   32
#define HID   8
#define NROWS 4096   // S_LEN * B_SZ

typedef float v2f __attribute__((ext_vector_type(2)));
typedef float v4f __attribute__((ext_vector_type(4)));

#if defined(__has_builtin) && __has_builtin(__builtin_elementwise_fma)
__device__ __forceinline__ v2f fma2(v2f a, v2f b, v2f c) {
    return __builtin_elementwise_fma(a, b, c);
}
#else
__device__ __forceinline__ v2f fma2(v2f a, v2f b, v2f c) {
    v2f r; r.x = fmaf(a.x, b.x, c.x); r.y = fmaf(a.y, b.y, c.y); return r;
}
#endif

// ---------------------------------------------------------------------------
// Kernel 1 (mega-fused prep):
//   blocks 0..7  : x-projection (phase A, 256 threads into LDS) + Elman scan
//                  (phase B, wave 0). Block g: dir = g>>2, b in [(g&3)*8, +8).
//   blocks 8..70 : repack weight_o [16][32000] -> wo_p [16000][16][2].
// xp LDS stride 65: phase-A writes land on 32 distinct banks (2-way aliasing
// = free), scan reads are lane-consecutive (conflict-free).
// All math orders identical to the previous (passing, absmax 0.0) version.
// ---------------------------------------------------------------------------
#define XP_STRIDE 65
__global__ __launch_bounds__(256) void fused_pre_kernel(
        const int* __restrict__ idx,
        const float* __restrict__ lookup,
        const float* __restrict__ wxf,
        const float* __restrict__ wxb,
        const float* __restrict__ whf,
        const float* __restrict__ whb,
        const float* __restrict__ Hf0,
        const float* __restrict__ Hb0,
        const float* __restrict__ bias_x,
        const float* __restrict__ bias_hf,
        const float* __restrict__ bias_hb,
        const float* __restrict__ wo,
        float* __restrict__ wo_p,
        float* __restrict__ Hws) {
    __shared__ float xp[S_LEN * XP_STRIDE];   // 128 x (8*8 padded to 65) = 33.3 KB
    int t = threadIdx.x;

    if (blockIdx.x < 8) {
        int blk   = blockIdx.x;
        int dir   = blk >> 2;        // 0..3 fwd, 4..7 bwd
        int bbase = (blk & 3) * 8;   // 8 batches per block
        const float* wx = dir ? wxb : wxf;
        const float* bh = dir ? bias_hb : bias_hf;

        // ---- phase A: all 256 threads compute xp[s][bl][j] for this block
        {
            int s   = t >> 1;          // 0..127
            int bh4 = (t & 1) * 4;     // which half of the 8 local batches
            #pragma unroll
            for (int bb = 0; bb < 4; ++bb) {
                int bl = bh4 + bb;
                int e = idx[s * B_SZ + bbase + bl];
                const float4* xr4 =
                    reinterpret_cast<const float4*>(lookup + (size_t)e * EMB);
                float x[EMB];
                #pragma unroll
                for (int q = 0; q < 8; ++q) {
                    float4 f = xr4[q];
                    x[4 * q + 0] = f.x; x[4 * q + 1] = f.y;
                    x[4 * q + 2] = f.z; x[4 * q + 3] = f.w;
                }
                #pragma unroll
                for (int j = 0; j < HID; ++j) {
                    float fa = bias_x[j] + bh[j];   // same order as before
                    #pragma unroll
                    for (int e2 = 0; e2 < EMB; ++e2)
                        fa += x[e2] * wx[e2 * HID + j];
                    xp[s * XP_STRIDE + bl * HID + j] = fa;
                }
            }
        }
        __syncthreads();

        // ---- phase B: wave 0 runs the recurrence
        if (t < 64) {
            int j  = t & 7;
            int bl = t >> 3;            // local batch 0..7
            int b  = bbase + bl;
            const float* wh = dir ? whb : whf;
            float w[HID];
            #pragma unroll
            for (int k = 0; k < HID; ++k) w[k] = wh[k * HID + j];
            float h = dir ? Hb0[j] : Hf0[j];

            for (int step = 0; step < S_LEN; ++step) {
                int s = dir ? (S_LEN - 1 - step) : step;
                float xv = xp[s * XP_STRIDE + bl * HID + j];
                int r = s * B_SZ + b;
                Hws[(size_t)r * 16 + dir * HID + j] = h;  // pre-update state
                float acc = xv;
                #pragma unroll
                for (int k = 0; k < HID; ++k)
                    acc += __shfl(h, k, 8) * w[k];
                // tanh(x) = 1 - 2/(e^{2x}+1)
                float ex = __expf(2.0f * acc);
                h = 1.0f - 2.0f * __builtin_amdgcn_rcpf(ex + 1.0f);
            }
        }
        return;
    }

    // ---- repack half (blocks 8..70)
    int v2 = (blockIdx.x - 8) * 256 + t;
    if (v2 >= VOCAB / 2) return;
    float2 buf[16];
    #pragma unroll
    for (int k = 0; k < 16; ++k)
        buf[k] = *reinterpret_cast<const float2*>(wo + (size_t)k * VOCAB + 2 * v2);
    float4* dst = reinterpret_cast<float4*>(wo_p + (size_t)v2 * 32);
    #pragma unroll
    for (int q = 0; q < 8; ++q)
        dst[q] = make_float4(buf[2 * q].x, buf[2 * q].y,
                             buf[2 * q + 1].x, buf[2 * q + 1].y);
}

// ---------------------------------------------------------------------------
// Kernel 2 (pass A): partial sums of exp(logits). 4 ROWS PER THREAD
// (r0, r0+1024, r0+2048, r0+3072): quarters the uniform weight-load traffic
// per FLOP. Per-row p/k/exp order unchanged -> Zpart bitwise identical.
// Zpart[chunk][row], 125 x 4096.
// ---------------------------------------------------------------------------
#define VCH_A 256
#define NCH_A (VOCAB / VCH_A)   // 125
__global__ __launch_bounds__(256) void passA_kernel(
        const float* __restrict__ Hws,
        const float* __restrict__ wo_p,
        const float* __restrict__ bias_o,
        float* __restrict__ Zpart) {
    int r0 = blockIdx.y * 256 + threadIdx.x;   // 0..1023
    int p0 = blockIdx.x * (VCH_A / 2);         // pair-index base

    float h[4][16];
    #pragma unroll
    for (int rr = 0; rr < 4; ++rr) {
        const float4* h4 =
            reinterpret_cast<const float4*>(Hws + (size_t)(r0 + 1024 * rr) * 16);
        #pragma unroll
        for (int q = 0; q < 4; ++q) {
            float4 f = h4[q];
            h[rr][4 * q + 0] = f.x; h[rr][4 * q + 1] = f.y;
            h[rr][4 * q + 2] = f.z; h[rr][4 * q + 3] = f.w;
        }
    }

    float z[4] = {0.0f, 0.0f, 0.0f, 0.0f};
    #pragma unroll 2
    for (int p = 0; p < VCH_A / 2; ++p) {
        const v2f* wp = reinterpret_cast<const v2f*>(wo_p + (size_t)(p0 + p) * 32);
        float2 bb = *reinterpret_cast<const float2*>(bias_o + (size_t)(p0 + p) * 2);
        v2f acc[4];
        #pragma unroll
        for (int rr = 0; rr < 4; ++rr) { acc[rr].x = bb.x; acc[rr].y = bb.y; }
        #pragma unroll
        for (int k = 0; k < 16; ++k) {
            v2f w = wp[k];
            #pragma unroll
            for (int rr = 0; rr < 4; ++rr) {
                v2f hk; hk.x = h[rr][k]; hk.y = h[rr][k];
                acc[rr] = fma2(hk, w, acc[rr]);
            }
        }
        #pragma unroll
        for (int rr = 0; rr < 4; ++rr)
            z[rr] += __expf(acc[rr].x) + __expf(acc[rr].y);
    }
    #pragma unroll
    for (int rr = 0; rr < 4; ++rr)
        Zpart[(size_t)blockIdx.x * NROWS + r0 + 1024 * rr] = z[rr];
}

// ---------------------------------------------------------------------------
// Kernel 3 (pass B + logZ): phase 0 computes logZ for the block's 128 rows
// (identical i-order sum as the old logz kernel -> bitwise same) and stages
// the Hws tile into LDS; phase 1 recomputes logits and writes out.
// Nontemporal float4 stores keep the 524 MB stream out of L2.
// ---------------------------------------------------------------------------
#define MT_B 128
__global__ __launch_bounds__(256) void passB_kernel(
        const float* __restrict__ Hws,
        const float* __restrict__ wo,
        const float* __restrict__ bias_o,
        const float* __restrict__ Zpart,
        float* __restrict__ out) {
    __shared__ __attribute__((aligned(16))) float hsh[MT_B * 16];
    __shared__ float lz_sh[MT_B];
    int t = threadIdx.x;
    int r0 = blockIdx.y * MT_B;

    {
        const float4* src = reinterpret_cast<const float4*>(Hws + (size_t)r0 * 16);
        float4* dst = reinterpret_cast<float4*>(hsh);
        dst[t]       = src[t];        // 256 * 16 B = first 4 KB
        dst[t + 256] = src[t + 256];  // second 4 KB
        if (t < MT_B) {
            float s = 0.0f;
            for (int i = 0; i < NCH_A; ++i)        // same order as old logz
                s += Zpart[(size_t)i * NROWS + r0 + t];
            lz_sh[t] = logf(s);
        }
    }
    __syncthreads();   // all threads reach this (vocab guard comes after)

    int v = (blockIdx.x * 256 + t) * 4;
    if (v < VOCAB) {
        v2f w01[16], w23[16];
        #pragma unroll
        for (int k = 0; k < 16; ++k) {
            float4 w4 = *reinterpret_cast<const float4*>(wo + (size_t)k * VOCAB + v);
            w01[k].x = w4.x; w01[k].y = w4.y;
            w23[k].x = w4.z; w23[k].y = w4.w;
        }
        float4 bv = *reinterpret_cast<const float4*>(bias_o + v);
        v2f b01; b01.x = bv.x; b01.y = bv.y;
        v2f b23; b23.x = bv.z; b23.y = bv.w;

        #pragma unroll 2
        for (int rr = 0; rr < MT_B; ++rr) {
            const float* hr = hsh + rr * 16;           // broadcast ds_read
            v2f t01 = b01, t23 = b23;
            #pragma unroll
            for (int k = 0; k < 16; ++k) {
                float hk = hr[k];
                v2f hk2; hk2.x = hk; hk2.y = hk;
                t01 = fma2(hk2, w01[k], t01);
                t23 = fma2(hk2, w23[k], t23);
            }
            float lz = lz_sh[rr];
            v4f o;
            o.x = t01.x - lz; o.y = t01.y - lz;
            o.z = t23.x - lz; o.w = t23.y - lz;
            __builtin_nontemporal_store(
                o, reinterpret_cast<v4f*>(out + (size_t)(r0 + rr) * VOCAB + v));
        }
    }
}

// ---------------------------------------------------------------------------
extern "C" void kernel_launch(void* const* d_in, const int* in_sizes, int n_in,
                              void* d_out, int out_size, void* d_ws, size_t ws_size,
                              hipStream_t stream) {
    const int*   idx     = (const int*)d_in[0];
    const float* lookup  = (const float*)d_in[1];
    const float* wxf     = (const float*)d_in[2];
    const float* whf     = (const float*)d_in[3];
    const float* wxb     = (const float*)d_in[4];
    const float* whb     = (const float*)d_in[5];
    const float* wo      = (const float*)d_in[6];
    const float* Hf0     = (const float*)d_in[7];
    const float* Hb0     = (const float*)d_in[8];
    const float* bias_x  = (const float*)d_in[9];
    const float* bias_hf = (const float*)d_in[10];
    const float* bias_hb = (const float*)d_in[11];
    const float* bias_o  = (const float*)d_in[12];
    float* out = (float*)d_out;

    float* ws    = (float*)d_ws;
    float* Hws   = ws;                  //  65536 floats (4096 x 16)
    float* wo_p  = ws + 65536;          // 512000 (16000 x 16 x 2)
    float* Zpart = ws + 577536;         // 512000 (125 x 4096)
    // total ~4.36 MB of ws

    fused_pre_kernel<<<71, 256, 0, stream>>>(idx, lookup, wxf, wxb, whf, whb,
                                             Hf0, Hb0, bias_x, bias_hf, bias_hb,
                                             wo, wo_p, Hws);
    passA_kernel<<<dim3(NCH_A, 4), 256, 0, stream>>>(Hws, wo_p, bias_o, Zpart);
    passB_kernel<<<dim3(32, NROWS / MT_B), 256, 0, stream>>>(Hws, wo, bias_o,
                                                             Zpart, out);
}

// Round 3
// 655.380 us; speedup vs baseline: 1.0086x; 1.0086x over previous
//
#include <hip/hip_runtime.h>
#include <hip/hip_bf16.h>

#define S_LEN 128
#define B_SZ  32
#define VOCAB 32000
#define EMB   32
#define HID   8
#define NROWS 4096   // S_LEN * B_SZ

typedef float v2f __attribute__((ext_vector_type(2)));
typedef float v4f __attribute__((ext_vector_type(4)));

#if defined(__has_builtin) && __has_builtin(__builtin_elementwise_fma)
__device__ __forceinline__ v2f fma2(v2f a, v2f b, v2f c) {
    return __builtin_elementwise_fma(a, b, c);
}
#else
__device__ __forceinline__ v2f fma2(v2f a, v2f b, v2f c) {
    v2f r; r.x = fmaf(a.x, b.x, c.x); r.y = fmaf(a.y, b.y, c.y); return r;
}
#endif

// ---------------------------------------------------------------------------
// Kernel 1 (fused prep, unchanged from R2 — proven harmless):
//   blocks 0..7  : x-projection (256 threads -> LDS) + Elman scan (wave 0).
//   blocks 8..70 : repack weight_o [16][32000] -> wo_p [16000][16][2].
// xp LDS stride 65: 2-way bank aliasing on writes (free), conflict-free reads.
// ---------------------------------------------------------------------------
#define XP_STRIDE 65
__global__ __launch_bounds__(256) void fused_pre_kernel(
        const int* __restrict__ idx,
        const float* __restrict__ lookup,
        const float* __restrict__ wxf,
        const float* __restrict__ wxb,
        const float* __restrict__ whf,
        const float* __restrict__ whb,
        const float* __restrict__ Hf0,
        const float* __restrict__ Hb0,
        const float* __restrict__ bias_x,
        const float* __restrict__ bias_hf,
        const float* __restrict__ bias_hb,
        const float* __restrict__ wo,
        float* __restrict__ wo_p,
        float* __restrict__ Hws) {
    __shared__ float xp[S_LEN * XP_STRIDE];
    int t = threadIdx.x;

    if (blockIdx.x < 8) {
        int blk   = blockIdx.x;
        int dir   = blk >> 2;        // 0..3 fwd, 4..7 bwd
        int bbase = (blk & 3) * 8;   // 8 batches per block
        const float* wx = dir ? wxb : wxf;
        const float* bh = dir ? bias_hb : bias_hf;

        // ---- phase A: all 256 threads compute xp[s][bl][j] for this block
        {
            int s   = t >> 1;          // 0..127
            int bh4 = (t & 1) * 4;     // which half of the 8 local batches
            #pragma unroll
            for (int bb = 0; bb < 4; ++bb) {
                int bl = bh4 + bb;
                int e = idx[s * B_SZ + bbase + bl];
                const float4* xr4 =
                    reinterpret_cast<const float4*>(lookup + (size_t)e * EMB);
                float x[EMB];
                #pragma unroll
                for (int q = 0; q < 8; ++q) {
                    float4 f = xr4[q];
                    x[4 * q + 0] = f.x; x[4 * q + 1] = f.y;
                    x[4 * q + 2] = f.z; x[4 * q + 3] = f.w;
                }
                #pragma unroll
                for (int j = 0; j < HID; ++j) {
                    float fa = bias_x[j] + bh[j];
                    #pragma unroll
                    for (int e2 = 0; e2 < EMB; ++e2)
                        fa += x[e2] * wx[e2 * HID + j];
                    xp[s * XP_STRIDE + bl * HID + j] = fa;
                }
            }
        }
        __syncthreads();

        // ---- phase B: wave 0 runs the recurrence
        if (t < 64) {
            int j  = t & 7;
            int bl = t >> 3;            // local batch 0..7
            int b  = bbase + bl;
            const float* wh = dir ? whb : whf;
            float w[HID];
            #pragma unroll
            for (int k = 0; k < HID; ++k) w[k] = wh[k * HID + j];
            float h = dir ? Hb0[j] : Hf0[j];

            for (int step = 0; step < S_LEN; ++step) {
                int s = dir ? (S_LEN - 1 - step) : step;
                float xv = xp[s * XP_STRIDE + bl * HID + j];
                int r = s * B_SZ + b;
                Hws[(size_t)r * 16 + dir * HID + j] = h;  // pre-update state
                float acc = xv;
                #pragma unroll
                for (int k = 0; k < HID; ++k)
                    acc += __shfl(h, k, 8) * w[k];
                // tanh(x) = 1 - 2/(e^{2x}+1)
                float ex = __expf(2.0f * acc);
                h = 1.0f - 2.0f * __builtin_amdgcn_rcpf(ex + 1.0f);
            }
        }
        return;
    }

    // ---- repack half (blocks 8..70)
    int v2 = (blockIdx.x - 8) * 256 + t;
    if (v2 >= VOCAB / 2) return;
    float2 buf[16];
    #pragma unroll
    for (int k = 0; k < 16; ++k)
        buf[k] = *reinterpret_cast<const float2*>(wo + (size_t)k * VOCAB + 2 * v2);
    float4* dst = reinterpret_cast<float4*>(wo_p + (size_t)v2 * 32);
    #pragma unroll
    for (int q = 0; q < 8; ++q)
        dst[q] = make_float4(buf[2 * q].x, buf[2 * q].y,
                             buf[2 * q + 1].x, buf[2 * q + 1].y);
}

// ---------------------------------------------------------------------------
// Kernel 2 (pass A): REVERTED to the R1 2-rows-per-thread form — the config
// from the measured −22 µs round. ~60 VGPR -> 16 waves/CU of latency hiding
// for the block-uniform scalar weight loads (4-row R2 version halved
// occupancy for no gain). Per-row p/k/exp order unchanged -> Zpart bitwise
// identical. Zpart[chunk][row], 125 x 4096.
// ---------------------------------------------------------------------------
#define VCH_A 256
#define NCH_A (VOCAB / VCH_A)   // 125
__global__ __launch_bounds__(256) void passA_kernel(
        const float* __restrict__ Hws,
        const float* __restrict__ wo_p,
        const float* __restrict__ bias_o,
        float* __restrict__ Zpart) {
    int ra = blockIdx.y * 256 + threadIdx.x;      // 0..2047
    int rb = ra + (NROWS / 2);                    // 2048..4095
    int p0 = blockIdx.x * (VCH_A / 2);            // pair-index base

    float ha[16], hb[16];
    const float4* ha4 = reinterpret_cast<const float4*>(Hws + (size_t)ra * 16);
    const float4* hb4 = reinterpret_cast<const float4*>(Hws + (size_t)rb * 16);
    #pragma unroll
    for (int q = 0; q < 4; ++q) {
        float4 fa = ha4[q];
        float4 fb = hb4[q];
        ha[4 * q + 0] = fa.x; ha[4 * q + 1] = fa.y;
        ha[4 * q + 2] = fa.z; ha[4 * q + 3] = fa.w;
        hb[4 * q + 0] = fb.x; hb[4 * q + 1] = fb.y;
        hb[4 * q + 2] = fb.z; hb[4 * q + 3] = fb.w;
    }

    float za = 0.0f, zb = 0.0f;
    #pragma unroll 2
    for (int p = 0; p < VCH_A / 2; ++p) {
        const v2f* wp = reinterpret_cast<const v2f*>(wo_p + (size_t)(p0 + p) * 32);
        float2 bb = *reinterpret_cast<const float2*>(bias_o + (size_t)(p0 + p) * 2);
        v2f acca; acca.x = bb.x; acca.y = bb.y;
        v2f accb = acca;
        #pragma unroll
        for (int k = 0; k < 16; ++k) {
            v2f w = wp[k];
            v2f hka; hka.x = ha[k]; hka.y = ha[k];
            v2f hkb; hkb.x = hb[k]; hkb.y = hb[k];
            acca = fma2(hka, w, acca);
            accb = fma2(hkb, w, accb);
        }
        za += __expf(acca.x) + __expf(acca.y);
        zb += __expf(accb.x) + __expf(accb.y);
    }
    Zpart[(size_t)blockIdx.x * NROWS + ra] = za;
    Zpart[(size_t)blockIdx.x * NROWS + rb] = zb;
}

// ---------------------------------------------------------------------------
// Kernel 3: logZ[r] = log(sum over 125 chunk partials). RESTORED as its own
// tiny kernel: R2's fold-into-passB made every one of the 32 x-blocks per
// row-tile redundantly run this 125-load chain (32x redundant preamble in
// front of all 1024 passB blocks). Here it runs once per row.
// ---------------------------------------------------------------------------
__global__ __launch_bounds__(256) void logz_kernel(
        const float* __restrict__ Zpart, float* __restrict__ logZ) {
    int r = blockIdx.x * blockDim.x + threadIdx.x;
    if (r >= NROWS) return;
    float s = 0.0f;
    for (int i = 0; i < NCH_A; ++i) s += Zpart[(size_t)i * NROWS + r];
    logZ[r] = logf(s);
}

// ---------------------------------------------------------------------------
// Kernel 4 (pass B): out[r][v] = logit - logZ[r]. MT_B 128 -> 64: grid
// 32x64 = 2048 blocks (8/CU), halves the per-block LDS-staging preamble and
// improves store-stream overlap + tail balance. Per-row math order
// unchanged. Nontemporal float4 stores keep the 524 MB stream out of L2.
// ---------------------------------------------------------------------------
#define MT_B 64
__global__ __launch_bounds__(256) void passB_kernel(
        const float* __restrict__ Hws,
        const float* __restrict__ wo,
        const float* __restrict__ bias_o,
        const float* __restrict__ logZ,
        float* __restrict__ out) {
    __shared__ __attribute__((aligned(16))) float hsh[MT_B * 16];
    __shared__ float lz_sh[MT_B];
    int t = threadIdx.x;
    int r0 = blockIdx.y * MT_B;

    {
        const float4* src = reinterpret_cast<const float4*>(Hws + (size_t)r0 * 16);
        float4* dst = reinterpret_cast<float4*>(hsh);
        dst[t] = src[t];              // 256 * 16 B = 4 KB = 64 rows x 16 f
        if (t < MT_B) lz_sh[t] = logZ[r0 + t];
    }
    __syncthreads();   // all threads reach this (vocab guard comes after)

    int v = (blockIdx.x * 256 + t) * 4;
    if (v < VOCAB) {
        v2f w01[16], w23[16];
        #pragma unroll
        for (int k = 0; k < 16; ++k) {
            float4 w4 = *reinterpret_cast<const float4*>(wo + (size_t)k * VOCAB + v);
            w01[k].x = w4.x; w01[k].y = w4.y;
            w23[k].x = w4.z; w23[k].y = w4.w;
        }
        float4 bv = *reinterpret_cast<const float4*>(bias_o + v);
        v2f b01; b01.x = bv.x; b01.y = bv.y;
        v2f b23; b23.x = bv.z; b23.y = bv.w;

        #pragma unroll 2
        for (int rr = 0; rr < MT_B; ++rr) {
            const float* hr = hsh + rr * 16;           // broadcast ds_read
            v2f t01 = b01, t23 = b23;
            #pragma unroll
            for (int k = 0; k < 16; ++k) {
                float hk = hr[k];
                v2f hk2; hk2.x = hk; hk2.y = hk;
                t01 = fma2(hk2, w01[k], t01);
                t23 = fma2(hk2, w23[k], t23);
            }
            float lz = lz_sh[rr];
            v4f o;
            o.x = t01.x - lz; o.y = t01.y - lz;
            o.z = t23.x - lz; o.w = t23.y - lz;
            __builtin_nontemporal_store(
                o, reinterpret_cast<v4f*>(out + (size_t)(r0 + rr) * VOCAB + v));
        }
    }
}

// ---------------------------------------------------------------------------
extern "C" void kernel_launch(void* const* d_in, const int* in_sizes, int n_in,
                              void* d_out, int out_size, void* d_ws, size_t ws_size,
                              hipStream_t stream) {
    const int*   idx     = (const int*)d_in[0];
    const float* lookup  = (const float*)d_in[1];
    const float* wxf     = (const float*)d_in[2];
    const float* whf     = (const float*)d_in[3];
    const float* wxb     = (const float*)d_in[4];
    const float* whb     = (const float*)d_in[5];
    const float* wo      = (const float*)d_in[6];
    const float* Hf0     = (const float*)d_in[7];
    const float* Hb0     = (const float*)d_in[8];
    const float* bias_x  = (const float*)d_in[9];
    const float* bias_hf = (const float*)d_in[10];
    const float* bias_hb = (const float*)d_in[11];
    const float* bias_o  = (const float*)d_in[12];
    float* out = (float*)d_out;

    float* ws    = (float*)d_ws;
    float* Hws   = ws;                  //  65536 floats (4096 x 16)
    float* wo_p  = ws + 65536;          // 512000 (16000 x 16 x 2)
    float* Zpart = ws + 577536;         // 512000 (125 x 4096)
    float* logZ  = ws + 1089536;        //   4096
    // total ~4.38 MB of ws

    fused_pre_kernel<<<71, 256, 0, stream>>>(idx, lookup, wxf, wxb, whf, whb,
                                             Hf0, Hb0, bias_x, bias_hf, bias_hb,
                                             wo, wo_p, Hws);
    passA_kernel<<<dim3(NCH_A, 8), 256, 0, stream>>>(Hws, wo_p, bias_o, Zpart);
    logz_kernel<<<16, 256, 0, stream>>>(Zpart, logZ);
    passB_kernel<<<dim3(32, NROWS / MT_B), 256, 0, stream>>>(Hws, wo, bias_o,
                                                             logZ, out);
}